// Round 5
// baseline (408.911 us; speedup 1.0000x reference)
//
#include <hip/hip_runtime.h>
#include <stdint.h>

// B=4, S=4096, H=1024, NS=2048. fp32 in/out; bf16 MFMA compute.
// Pipeline (v never materialized; attn normalized lazily):
//   y_sampled = softmax(q k^T/32) @ V2,  V2T = (Wo Wv) @ xs^T
//   L1: cast Wq,Wk -> Wqkb, Wo -> Wob, Wv -> WvT (transposed); gather xs.
//   L2: qk = xs @ Wqkb^T (1024) + Wvo = Wob @ WvT^T (64) + zero-y (448)
//   L3: E = exp(qk^T/32) -> attnB bf16 + row partial sums (no max subtraction:
//       scores ~ N(0,1), fp32-exact)  +  V2T = Wvo @ xs^T (512)
//   L4: y[idx rows] = (attnB @ V2T^T) * inv_rowsum (scatter). bx==0 blocks
//       also write attnF = bf16(E)*inv from the staged LDS A-tiles (the
//       staged tile IS attnB; writeback inverts the staging map).
//
// GEMM core: proven 128x128 tile, BK=64, 4 waves, octet-XOR swizzle,
// global_load_lds width-16 staging, 3 blocks/CU (the 372-377us-verified
// structure; 256²/8-phase attempts measured WORSE — 23% MfmaUtil, r1/r3/r4).
#define NB 4
#define BS 4096
#define BH 1024
#define NS 2048

typedef unsigned short u16;
typedef __attribute__((ext_vector_type(8))) short short8;
typedef __attribute__((ext_vector_type(4))) float float4v;

__device__ __forceinline__ void gload_lds16(const u16* g, u16* l) {
  __builtin_amdgcn_global_load_lds(
      (const __attribute__((address_space(1))) unsigned int*)g,
      (__attribute__((address_space(3))) unsigned int*)l,
      16, 0, 0);
}

__device__ __forceinline__ u16 f2bf(float f) {  // RNE float->bf16
  union { float f; unsigned u; } c; c.f = f;
  unsigned r = c.u + 0x7fff + ((c.u >> 16) & 1);
  return (u16)(r >> 16);
}

__device__ __forceinline__ float bf2f(short b) {
  union { unsigned u; float f; } c;
  c.u = ((unsigned)(unsigned short)b) << 16;
  return c.f;
}

// L1: casts + Wv transpose + gather. Grid 11520 x 256.
__global__ __launch_bounds__(256)
void cast_gather(const float* __restrict__ Wq, const float* __restrict__ Wk,
                 const float* __restrict__ Wv, const float* __restrict__ Wo,
                 const float* __restrict__ x, const int* __restrict__ idx,
                 u16* __restrict__ Wqkb, u16* __restrict__ Wob,
                 u16* __restrict__ WvT, u16* __restrict__ xs)
{
  __shared__ __align__(16) u16 tile[64][80];
  const int t = threadIdx.x;
  const int b = blockIdx.x;
  if (b < 3072) {
    long i = ((long)(b & 1023)) * 1024 + t * 4;
    const float* src; u16* dst;
    if (b < 1024)      { src = Wq + i; dst = Wqkb + i; }
    else if (b < 2048) { src = Wk + i; dst = Wqkb + (1l << 20) + i; }
    else               { src = Wo + i; dst = Wob + i; }
    float4 f = *(const float4*)src;
    u16 o[4] = { f2bf(f.x), f2bf(f.y), f2bf(f.z), f2bf(f.w) };
    *(uint2*)dst = *(const uint2*)o;
  } else if (b < 3328) {
    const int id = b - 3072;                 // 16x16 tiles of 64x64
    const int tr = id >> 4, tc = id & 15;
    const int hl = t >> 2, c0 = (t & 3) * 16;
    const float* src = Wv + ((long)(tr * 64 + hl)) * 1024 + tc * 64 + c0;
    u16 tmp[16];
#pragma unroll
    for (int j = 0; j < 4; ++j) {
      float4 f = ((const float4*)src)[j];
      tmp[j*4+0] = f2bf(f.x); tmp[j*4+1] = f2bf(f.y);
      tmp[j*4+2] = f2bf(f.z); tmp[j*4+3] = f2bf(f.w);
    }
    *(uint4*)&tile[hl][c0]     = *(const uint4*)&tmp[0];
    *(uint4*)&tile[hl][c0 + 8] = *(const uint4*)&tmp[8];
    __syncthreads();
    const int gl = t >> 2;
    u16 o[16];
#pragma unroll
    for (int j = 0; j < 16; ++j) o[j] = tile[c0 + j][gl];
    u16* dst = WvT + ((long)(tc * 64 + gl)) * 1024 + tr * 64 + c0;
    *(uint4*)dst       = *(const uint4*)&o[0];
    *(uint4*)(dst + 8) = *(const uint4*)&o[8];
  } else {
    const int id = b - 3328;
    const int bb = id >> 11, i = id & 2047;
    const float* src = x + ((long)bb * BS + idx[i]) * BH + t * 4;
    u16* dst = xs + ((long)bb * NS + i) * BH + t * 4;
    float4 f = *(const float4*)src;
    u16 o[4] = { f2bf(f.x), f2bf(f.y), f2bf(f.z), f2bf(f.w) };
    *(uint2*)dst = *(const uint2*)o;
  }
}

// ---------------------------------------------------------------------------
// Core 128x128 tile GEMM, BK=64: C = alpha * (A-rows x B-rows^T), bf16,
// K-contig. 4 waves (2x2 of 64x64). LDS 2x16KB, octet-XOR swizzle; staging
// and fragment reads both conflict-free. C rows optionally scattered via sC.
// EPI=0: plain store.
// EPI=1: vv=exp(vv); store bf16 to C; per-row 64-col partial sums ->
//        auxP[row*32 + bx*2 + wn]  (no atomics, no zeroing).
// EPI=2: pre-loop inv[128] from auxP (shared sInv2); in-loop, bx==0 blocks
//        write auxF rows = bf16(staged A-tile) * inv (attn output); epilogue
//        row-scales by inv before store.
// ---------------------------------------------------------------------------
template <typename OutT, int EPI>
__device__ __forceinline__ void gemm_core(
    u16* __restrict__ ldsA, u16* __restrict__ ldsB,
    const u16* __restrict__ Az, int lda,
    const u16* __restrict__ Bz, int ldb,
    OutT* __restrict__ Cz, const int* __restrict__ sC, int ldc,
    int K, float alpha, int bx, int by,
    float* __restrict__ auxP, float* __restrict__ auxF)
{
  __shared__ float sInv2[128];             // used only by EPI=2 (512 B)
  const int t = threadIdx.x;
  const int l = t & 63;
  const int wm = t >> 7, wn = (t >> 6) & 1;

  const int sr = t >> 3;                   // staging row 0..31
  const int scol = (t & 7) ^ (sr & 7);     // logical k-chunk to fetch
  const u16* aS = Az + (long)(by * 128 + sr) * lda + scol * 8;
  const u16* bS = Bz + (long)(bx * 128 + sr) * ldb + scol * 8;
  const long aStep = 32l * lda, bStep = 32l * ldb;

  int aOff[4][2], bOff[4][2];
#pragma unroll
  for (int i = 0; i < 4; ++i) {
#pragma unroll
    for (int h = 0; h < 2; ++h) {
      int rA = wm * 64 + i * 16 + (l & 15);
      aOff[i][h] = rA * 128 + (((h * 4 + (l >> 4)) ^ (rA & 7)) * 16);
      int rB = wn * 64 + i * 16 + (l & 15);
      bOff[i][h] = rB * 128 + (((h * 4 + (l >> 4)) ^ (rB & 7)) * 16);
    }
  }

  if constexpr (EPI == 2) {
    if (t < 128) {
      const float4* pp = (const float4*)(auxP + (long)(by * 128 + t) * 32);
      float s = 0.f;
#pragma unroll
      for (int j = 0; j < 8; ++j) { float4 f = pp[j]; s += f.x + f.y + f.z + f.w; }
      sInv2[t] = 1.0f / s;
    }
    __syncthreads();
  }

  float4v acc[4][4] = {};

  for (int k0 = 0; k0 < K; k0 += 64) {
    __syncthreads();
    gload_lds16(aS + k0,             ldsA + t * 8);
    gload_lds16(aS + aStep + k0,     ldsA + 2048 + t * 8);
    gload_lds16(aS + 2 * aStep + k0, ldsA + 4096 + t * 8);
    gload_lds16(aS + 3 * aStep + k0, ldsA + 6144 + t * 8);
    gload_lds16(bS + k0,             ldsB + t * 8);
    gload_lds16(bS + bStep + k0,     ldsB + 2048 + t * 8);
    gload_lds16(bS + 2 * bStep + k0, ldsB + 4096 + t * 8);
    gload_lds16(bS + 3 * bStep + k0, ldsB + 6144 + t * 8);
    __syncthreads();

    if constexpr (EPI == 2) {
      if (bx == 0) {
        // attn writeback: staged A-tile is bf16(E); invert the staging map.
#pragma unroll
        for (int q = 0; q < 4; ++q) {
          short8 w = *(const short8*)(ldsA + q * 2048 + t * 8);
          const int row = q * 32 + sr;
          const float iv = sInv2[row];
          float* dst = auxF + (long)(by * 128 + row) * NS + k0 + scol * 8;
          *(float4*)dst = make_float4(bf2f(w[0]) * iv, bf2f(w[1]) * iv,
                                      bf2f(w[2]) * iv, bf2f(w[3]) * iv);
          *(float4*)(dst + 4) = make_float4(bf2f(w[4]) * iv, bf2f(w[5]) * iv,
                                            bf2f(w[6]) * iv, bf2f(w[7]) * iv);
        }
      }
    }

#pragma unroll
    for (int h = 0; h < 2; ++h) {
      short8 af[4], bfr[4];
#pragma unroll
      for (int i = 0; i < 4; ++i) af[i]  = *(const short8*)((const char*)ldsA + aOff[i][h]);
#pragma unroll
      for (int i = 0; i < 4; ++i) bfr[i] = *(const short8*)((const char*)ldsB + bOff[i][h]);
#pragma unroll
      for (int mi = 0; mi < 4; ++mi)
#pragma unroll
        for (int ni = 0; ni < 4; ++ni)
          acc[mi][ni] = __builtin_amdgcn_mfma_f32_16x16x32_bf16(af[mi], bfr[ni], acc[mi][ni], 0, 0, 0);
    }
  }

  // Epilogue. C/D layout: col = l&15, row = (l>>4)*4 + reg.
#pragma unroll
  for (int mi = 0; mi < 4; ++mi) {
#pragma unroll
    for (int i = 0; i < 4; ++i) {
      const int rloc = wm * 64 + mi * 16 + ((l >> 4) * 4) + i;
      const int r = by * 128 + rloc;
      const long rowOff = (long)(sC ? sC[r] : r) * ldc;
      float rs = 1.0f;
      if constexpr (EPI == 2) rs = sInv2[rloc];
      float psum = 0.f;
#pragma unroll
      for (int ni = 0; ni < 4; ++ni) {
        const int c = bx * 128 + wn * 64 + ni * 16 + (l & 15);
        float vv = acc[mi][ni][i] * alpha;
        if constexpr (EPI == 1) {
          vv = __expf(vv);
          psum += vv;
          Cz[rowOff + c] = (OutT)f2bf(vv);
        } else if constexpr (EPI == 2) {
          Cz[rowOff + c] = (OutT)(vv * rs);
        } else {
          if constexpr (sizeof(OutT) == 2) Cz[rowOff + c] = (OutT)f2bf(vv);
          else                             Cz[rowOff + c] = (OutT)vv;
        }
      }
      if constexpr (EPI == 1) {
        psum += __shfl_xor(psum, 1);
        psum += __shfl_xor(psum, 2);
        psum += __shfl_xor(psum, 4);
        psum += __shfl_xor(psum, 8);
        if ((l & 15) == 0) auxP[(long)r * 32 + bx * 2 + wn] = psum;
      }
    }
  }
}

// L2: qk (by<16) + Wvo (by==16) + zero-y (by 17-23). Grid (16,24,NB) = 1536.
__global__ __launch_bounds__(256, 3)
void qk_wvo_zero(const u16* __restrict__ xs, const u16* __restrict__ Wqkb,
                 const u16* __restrict__ Wob, const u16* __restrict__ WvT,
                 u16* __restrict__ qk, u16* __restrict__ Wvo,
                 float* __restrict__ y)
{
  __shared__ __align__(16) u16 ldsA[128 * 64];
  __shared__ __align__(16) u16 ldsB[128 * 64];
  const long z = blockIdx.z;
  if (blockIdx.y < 16) {
    gemm_core<u16, 0>(ldsA, ldsB, xs + z * ((long)NS * BH), BH, Wqkb, BH,
                      qk + z * ((long)NS * 2048), nullptr, 2048, BH, 1.0f,
                      blockIdx.x, blockIdx.y, nullptr, nullptr);
  } else if (blockIdx.y == 16) {
    const int id = (int)z * 16 + blockIdx.x;   // 0..63 -> 8x8 tiles
    gemm_core<u16, 0>(ldsA, ldsB, Wob, BH, WvT, BH,
                      Wvo, nullptr, BH, BH, 1.0f,
                      id & 7, id >> 3, nullptr, nullptr);
  } else {
    const long id = (((long)blockIdx.y - 17) * 16 + blockIdx.x) * 4 + z; // 0..447
    const long total = 4194304;                // 64 MiB of y in float4
    const long per = 9363;
    const long e = min((id + 1) * per, total);
    float4* p = (float4*)y;
    for (long j = id * per + threadIdx.x; j < e; j += 256)
      p[j] = make_float4(0.f, 0.f, 0.f, 0.f);
  }
}

// L3: scores E=exp -> attnB bf16 + partials (by<16) + V2T (by 16-23).
// Grid (16,24,NB) = 1536.
__global__ __launch_bounds__(256, 3)
void scores_v2t(const u16* __restrict__ qk, const u16* __restrict__ Wvo,
                const u16* __restrict__ xs,
                u16* __restrict__ attnB, u16* __restrict__ V2T,
                float* __restrict__ partials)
{
  __shared__ __align__(16) u16 ldsA[128 * 64];
  __shared__ __align__(16) u16 ldsB[128 * 64];
  const long z = blockIdx.z;
  if (blockIdx.y < 16) {
    const u16* A = qk + z * ((long)NS * 2048);
    gemm_core<u16, 1>(ldsA, ldsB, A, 2048, A + 1024, 2048,
                      attnB + z * ((long)NS * NS), nullptr, NS, BH, 0.03125f,
                      blockIdx.x, blockIdx.y,
                      partials + z * ((long)NS * 32), nullptr);
  } else {
    gemm_core<u16, 0>(ldsA, ldsB, Wvo, BH, xs + z * ((long)NS * BH), BH,
                      V2T + z * ((long)BH * NS), nullptr, NS, BH, 1.0f,
                      blockIdx.x, blockIdx.y - 16, nullptr, nullptr);
  }
}

// L4: y[idx rows] = (attnB @ V2T^T) * inv (scatter); bx==0 also writes
// attnF = bf16(E) * inv from staged tiles. Grid (8,16,NB) = 512.
__global__ __launch_bounds__(256, 3)
void final_norm(const u16* __restrict__ attnB, const u16* __restrict__ V2T,
                const float* __restrict__ partials, const int* __restrict__ idx,
                float* __restrict__ y, float* __restrict__ attnF)
{
  __shared__ __align__(16) u16 ldsA[128 * 64];
  __shared__ __align__(16) u16 ldsB[128 * 64];
  const long z = blockIdx.z;
  gemm_core<float, 2>(ldsA, ldsB, attnB + z * ((long)NS * NS), NS,
                      V2T + z * ((long)BH * NS), NS,
                      y + z * ((long)BS * BH), idx, BH, NS, 1.0f,
                      blockIdx.x, blockIdx.y,
                      (float*)(partials + z * ((long)NS * 32)),
                      attnF + z * ((long)NS * NS));
}

extern "C" void kernel_launch(void* const* d_in, const int* in_sizes, int n_in,
                              void* d_out, int out_size, void* d_ws, size_t ws_size,
                              hipStream_t stream)
{
  const float* x   = (const float*)d_in[0];
  const int*   idx = (const int*)d_in[1];
  const float* Wq  = (const float*)d_in[2];
  const float* Wk  = (const float*)d_in[4];
  const float* Wv  = (const float*)d_in[6];
  const float* Wo  = (const float*)d_in[8];

  float* y     = (float*)d_out;                    // (B,S,H) fp32
  float* attnF = y + (long)NB * BS * BH;           // (B,NS,NS) fp32

  // Workspace, peak 107 MiB:
  char* ws = (char*)d_ws;
  float* partials = (float*)ws;                    // (B*NS,32) f32, 1 MiB
  u16* xs    = (u16*)(ws + (1l << 20));            // (B,NS,H)     16 MiB
  u16* qk    = (u16*)(ws + (17l << 20));           // (B,NS,2048)  32 MiB
  u16* V2T   = (u16*)(ws + (49l << 20));           // (B,H,NS)     16 MiB
  u16* attnB = (u16*)(ws + (65l << 20));           // (B,NS,NS)    32 MiB
  u16* Wqkb  = (u16*)(ws + (97l << 20));           // (2048,1024)   4 MiB
  u16* Wob   = (u16*)(ws + (101l << 20));          // (1024,1024)   2 MiB
  u16* WvT   = (u16*)(ws + (103l << 20));          // (1024,1024)   2 MiB
  u16* Wvo   = (u16*)(ws + (105l << 20));          // (1024,1024)   2 MiB

  dim3 blk(256);

  cast_gather<<<dim3(11520), blk, 0, stream>>>(Wq, Wk, Wv, Wo, x, idx,
                                               Wqkb, Wob, WvT, xs);

  qk_wvo_zero<<<dim3(16, 24, NB), blk, 0, stream>>>(xs, Wqkb, Wob, WvT,
                                                    qk, Wvo, y);

  scores_v2t<<<dim3(16, 24, NB), blk, 0, stream>>>(qk, Wvo, xs, attnB,
                                                   V2T, partials);

  final_norm<<<dim3(8, 16, NB), blk, 0, stream>>>(attnB, V2T, partials,
                                                  idx, y, attnF);
}

// Round 6
// 395.558 us; speedup vs baseline: 1.0338x; 1.0338x over previous
//
#include <hip/hip_runtime.h>
#include <stdint.h>

// B=4, S=4096, H=1024, NS=2048. fp32 in/out; bf16 MFMA compute.
// Pipeline (v never materialized; attn normalized lazily from bf16 E):
//   y_sampled = softmax(q k^T/32) @ V2,  V2T = (Wo Wv) @ xs^T
//   L1: cast Wq,Wk -> Wqkb, Wo -> Wob, Wv -> WvT (transposed); gather xs.
//   L2: qk = xs @ Wqkb^T (1024 blocks) + Wvo = Wob @ WvT^T (64)
//   L3: E = exp(qk^T/32) -> attnB bf16 + row partial sums (no max subtraction:
//       scores ~ N(0,1), fp32-exact)  +  V2T = Wvo @ xs^T (512) + zero-y (512)
//   L4: y[idx rows] = (attnB @ V2T^T) * inv_rowsum (scatter, 512)
//       + attnF = bf2f(attnB) * inv  (separate blocks, 512 — NO in-GEMM
//       writeback: r5 measured that as a 125us straggler kernel)
//
// GEMM core: proven 128x128 tile, BK=64, 4 waves, octet-XOR swizzle,
// global_load_lds width-16 staging, now 4 blocks/CU (launch_bounds(256,4);
// LDS 33KB x 4 = 132KB; VGPR 64+64 unified = 128 -> exactly 16 waves/CU).
#define NB 4
#define BS 4096
#define BH 1024
#define NS 2048

typedef unsigned short u16;
typedef __attribute__((ext_vector_type(8))) short short8;
typedef __attribute__((ext_vector_type(4))) float float4v;

__device__ __forceinline__ void gload_lds16(const u16* g, u16* l) {
  __builtin_amdgcn_global_load_lds(
      (const __attribute__((address_space(1))) unsigned int*)g,
      (__attribute__((address_space(3))) unsigned int*)l,
      16, 0, 0);
}

__device__ __forceinline__ u16 f2bf(float f) {  // RNE float->bf16
  union { float f; unsigned u; } c; c.f = f;
  unsigned r = c.u + 0x7fff + ((c.u >> 16) & 1);
  return (u16)(r >> 16);
}

__device__ __forceinline__ float bf2f(short b) {
  union { unsigned u; float f; } c;
  c.u = ((unsigned)(unsigned short)b) << 16;
  return c.f;
}

// L1: casts + Wv transpose + gather. Grid 11520 x 256.
__global__ __launch_bounds__(256)
void cast_gather(const float* __restrict__ Wq, const float* __restrict__ Wk,
                 const float* __restrict__ Wv, const float* __restrict__ Wo,
                 const float* __restrict__ x, const int* __restrict__ idx,
                 u16* __restrict__ Wqkb, u16* __restrict__ Wob,
                 u16* __restrict__ WvT, u16* __restrict__ xs)
{
  __shared__ __align__(16) u16 tile[64][80];
  const int t = threadIdx.x;
  const int b = blockIdx.x;
  if (b < 3072) {
    long i = ((long)(b & 1023)) * 1024 + t * 4;
    const float* src; u16* dst;
    if (b < 1024)      { src = Wq + i; dst = Wqkb + i; }
    else if (b < 2048) { src = Wk + i; dst = Wqkb + (1l << 20) + i; }
    else               { src = Wo + i; dst = Wob + i; }
    float4 f = *(const float4*)src;
    u16 o[4] = { f2bf(f.x), f2bf(f.y), f2bf(f.z), f2bf(f.w) };
    *(uint2*)dst = *(const uint2*)o;
  } else if (b < 3328) {
    const int id = b - 3072;                 // 16x16 tiles of 64x64
    const int tr = id >> 4, tc = id & 15;
    const int hl = t >> 2, c0 = (t & 3) * 16;
    const float* src = Wv + ((long)(tr * 64 + hl)) * 1024 + tc * 64 + c0;
    u16 tmp[16];
#pragma unroll
    for (int j = 0; j < 4; ++j) {
      float4 f = ((const float4*)src)[j];
      tmp[j*4+0] = f2bf(f.x); tmp[j*4+1] = f2bf(f.y);
      tmp[j*4+2] = f2bf(f.z); tmp[j*4+3] = f2bf(f.w);
    }
    *(uint4*)&tile[hl][c0]     = *(const uint4*)&tmp[0];
    *(uint4*)&tile[hl][c0 + 8] = *(const uint4*)&tmp[8];
    __syncthreads();
    const int gl = t >> 2;
    u16 o[16];
#pragma unroll
    for (int j = 0; j < 16; ++j) o[j] = tile[c0 + j][gl];
    u16* dst = WvT + ((long)(tc * 64 + gl)) * 1024 + tr * 64 + c0;
    *(uint4*)dst       = *(const uint4*)&o[0];
    *(uint4*)(dst + 8) = *(const uint4*)&o[8];
  } else {
    const int id = b - 3328;
    const int bb = id >> 11, i = id & 2047;
    const float* src = x + ((long)bb * BS + idx[i]) * BH + t * 4;
    u16* dst = xs + ((long)bb * NS + i) * BH + t * 4;
    float4 f = *(const float4*)src;
    u16 o[4] = { f2bf(f.x), f2bf(f.y), f2bf(f.z), f2bf(f.w) };
    *(uint2*)dst = *(const uint2*)o;
  }
}

// ---------------------------------------------------------------------------
// Core 128x128 tile GEMM, BK=64: C = alpha * (A-rows x B-rows^T), bf16,
// K-contig. 4 waves (2x2 of 64x64). LDS 2x16KB, octet-XOR swizzle; staging
// and fragment reads both conflict-free. C rows optionally scattered via sC.
// EPI=0: plain store.
// EPI=1: vv=exp(vv); store bf16 to C; per-row 64-col partial sums ->
//        auxP[row*32 + bx*2 + wn]  (no atomics, no zeroing).
// EPI=2: pre-loop inv[128] from auxP (shared sInv2); epilogue row-scales
//        by inv before store. (No in-loop global writes — r5 straggler fix.)
// ---------------------------------------------------------------------------
template <typename OutT, int EPI>
__device__ __forceinline__ void gemm_core(
    u16* __restrict__ ldsA, u16* __restrict__ ldsB,
    const u16* __restrict__ Az, int lda,
    const u16* __restrict__ Bz, int ldb,
    OutT* __restrict__ Cz, const int* __restrict__ sC, int ldc,
    int K, float alpha, int bx, int by,
    float* __restrict__ auxP)
{
  __shared__ float sInv2[128];             // used only by EPI=2 (512 B)
  const int t = threadIdx.x;
  const int l = t & 63;
  const int wm = t >> 7, wn = (t >> 6) & 1;

  const int sr = t >> 3;                   // staging row 0..31
  const int scol = (t & 7) ^ (sr & 7);     // logical k-chunk to fetch
  const u16* aS = Az + (long)(by * 128 + sr) * lda + scol * 8;
  const u16* bS = Bz + (long)(bx * 128 + sr) * ldb + scol * 8;
  const long aStep = 32l * lda, bStep = 32l * ldb;

  int aOff[4][2], bOff[4][2];
#pragma unroll
  for (int i = 0; i < 4; ++i) {
#pragma unroll
    for (int h = 0; h < 2; ++h) {
      int rA = wm * 64 + i * 16 + (l & 15);
      aOff[i][h] = rA * 128 + (((h * 4 + (l >> 4)) ^ (rA & 7)) * 16);
      int rB = wn * 64 + i * 16 + (l & 15);
      bOff[i][h] = rB * 128 + (((h * 4 + (l >> 4)) ^ (rB & 7)) * 16);
    }
  }

  if constexpr (EPI == 2) {
    if (t < 128) {
      const float4* pp = (const float4*)(auxP + (long)(by * 128 + t) * 32);
      float s = 0.f;
#pragma unroll
      for (int j = 0; j < 8; ++j) { float4 f = pp[j]; s += f.x + f.y + f.z + f.w; }
      sInv2[t] = 1.0f / s;
    }
    __syncthreads();
  }

  float4v acc[4][4] = {};

  for (int k0 = 0; k0 < K; k0 += 64) {
    __syncthreads();
    gload_lds16(aS + k0,             ldsA + t * 8);
    gload_lds16(aS + aStep + k0,     ldsA + 2048 + t * 8);
    gload_lds16(aS + 2 * aStep + k0, ldsA + 4096 + t * 8);
    gload_lds16(aS + 3 * aStep + k0, ldsA + 6144 + t * 8);
    gload_lds16(bS + k0,             ldsB + t * 8);
    gload_lds16(bS + bStep + k0,     ldsB + 2048 + t * 8);
    gload_lds16(bS + 2 * bStep + k0, ldsB + 4096 + t * 8);
    gload_lds16(bS + 3 * bStep + k0, ldsB + 6144 + t * 8);
    __syncthreads();

#pragma unroll
    for (int h = 0; h < 2; ++h) {
      short8 af[4], bfr[4];
#pragma unroll
      for (int i = 0; i < 4; ++i) af[i]  = *(const short8*)((const char*)ldsA + aOff[i][h]);
#pragma unroll
      for (int i = 0; i < 4; ++i) bfr[i] = *(const short8*)((const char*)ldsB + bOff[i][h]);
#pragma unroll
      for (int mi = 0; mi < 4; ++mi)
#pragma unroll
        for (int ni = 0; ni < 4; ++ni)
          acc[mi][ni] = __builtin_amdgcn_mfma_f32_16x16x32_bf16(af[mi], bfr[ni], acc[mi][ni], 0, 0, 0);
    }
  }

  // Epilogue. C/D layout: col = l&15, row = (l>>4)*4 + reg.
#pragma unroll
  for (int mi = 0; mi < 4; ++mi) {
#pragma unroll
    for (int i = 0; i < 4; ++i) {
      const int rloc = wm * 64 + mi * 16 + ((l >> 4) * 4) + i;
      const int r = by * 128 + rloc;
      const long rowOff = (long)(sC ? sC[r] : r) * ldc;
      float rs = 1.0f;
      if constexpr (EPI == 2) rs = sInv2[rloc];
      float psum = 0.f;
#pragma unroll
      for (int ni = 0; ni < 4; ++ni) {
        const int c = bx * 128 + wn * 64 + ni * 16 + (l & 15);
        float vv = acc[mi][ni][i] * alpha;
        if constexpr (EPI == 1) {
          vv = __expf(vv);
          psum += vv;
          Cz[rowOff + c] = (OutT)f2bf(vv);
        } else if constexpr (EPI == 2) {
          Cz[rowOff + c] = (OutT)(vv * rs);
        } else {
          if constexpr (sizeof(OutT) == 2) Cz[rowOff + c] = (OutT)f2bf(vv);
          else                             Cz[rowOff + c] = (OutT)vv;
        }
      }
      if constexpr (EPI == 1) {
        psum += __shfl_xor(psum, 1);
        psum += __shfl_xor(psum, 2);
        psum += __shfl_xor(psum, 4);
        psum += __shfl_xor(psum, 8);
        if ((l & 15) == 0) auxP[(long)r * 32 + bx * 2 + wn] = psum;
      }
    }
  }
}

// L2: qk (by<16) + Wvo (by==16). Grid (16,17,NB) = 1088.
__global__ __launch_bounds__(256, 4)
void qk_wvo(const u16* __restrict__ xs, const u16* __restrict__ Wqkb,
            const u16* __restrict__ Wob, const u16* __restrict__ WvT,
            u16* __restrict__ qk, u16* __restrict__ Wvo)
{
  __shared__ __align__(16) u16 ldsA[128 * 64];
  __shared__ __align__(16) u16 ldsB[128 * 64];
  const long z = blockIdx.z;
  if (blockIdx.y < 16) {
    gemm_core<u16, 0>(ldsA, ldsB, xs + z * ((long)NS * BH), BH, Wqkb, BH,
                      qk + z * ((long)NS * 2048), nullptr, 2048, BH, 1.0f,
                      blockIdx.x, blockIdx.y, nullptr);
  } else {
    const int id = (int)z * 16 + blockIdx.x;   // 0..63 -> 8x8 tiles
    gemm_core<u16, 0>(ldsA, ldsB, Wob, BH, WvT, BH,
                      Wvo, nullptr, BH, BH, 1.0f,
                      id & 7, id >> 3, nullptr);
  }
}

// L3: scores E=exp -> attnB bf16 + partials (by<16) + V2T (by 16-23)
//     + zero-y (by 24-31). Grid (16,32,NB) = 2048.
__global__ __launch_bounds__(256, 4)
void scores_v2t_zero(const u16* __restrict__ qk, const u16* __restrict__ Wvo,
                     const u16* __restrict__ xs,
                     u16* __restrict__ attnB, u16* __restrict__ V2T,
                     float* __restrict__ partials, float* __restrict__ y)
{
  __shared__ __align__(16) u16 ldsA[128 * 64];
  __shared__ __align__(16) u16 ldsB[128 * 64];
  const long z = blockIdx.z;
  if (blockIdx.y < 16) {
    const u16* A = qk + z * ((long)NS * 2048);
    gemm_core<u16, 1>(ldsA, ldsB, A, 2048, A + 1024, 2048,
                      attnB + z * ((long)NS * NS), nullptr, NS, BH, 0.03125f,
                      blockIdx.x, blockIdx.y,
                      partials + z * ((long)NS * 32));
  } else if (blockIdx.y < 24) {
    gemm_core<u16, 0>(ldsA, ldsB, Wvo, BH, xs + z * ((long)NS * BH), BH,
                      V2T + z * ((long)BH * NS), nullptr, NS, BH, 1.0f,
                      blockIdx.x, blockIdx.y - 16, nullptr);
  } else {
    long id = (((long)blockIdx.y - 24) * 16 + blockIdx.x) * 4 + z;  // 0..511
    float4* p = (float4*)y + id * 8192 + threadIdx.x;
#pragma unroll
    for (int j = 0; j < 32; ++j) p[j * 256] = make_float4(0.f, 0.f, 0.f, 0.f);
  }
}

// L4: y[idx rows] = (attnB @ V2T^T) * inv (scatter, by<16) + attnF =
// bf2f(attnB) * inv (by 16-31, 128 slots/z x 16 rows). Grid (8,32,NB) = 1024.
__global__ __launch_bounds__(256, 4)
void final_norm(const u16* __restrict__ attnB, const u16* __restrict__ V2T,
                const float* __restrict__ partials, const int* __restrict__ idx,
                float* __restrict__ y, float* __restrict__ attnF)
{
  __shared__ __align__(16) u16 ldsA[128 * 64];
  __shared__ __align__(16) u16 ldsB[128 * 64];
  const long z = blockIdx.z;
  if (blockIdx.y < 16) {
    gemm_core<float, 2>(ldsA, ldsB, attnB + z * ((long)NS * NS), NS,
                        V2T + z * ((long)BH * NS), NS,
                        y + z * ((long)BS * BH), idx, BH, NS, 1.0f,
                        blockIdx.x, blockIdx.y,
                        (float*)(partials + z * ((long)NS * 32)));
  } else {
    __shared__ float sInv[16];
    const int t = threadIdx.x;
    const int slot = (blockIdx.y - 16) * 8 + blockIdx.x;   // 0..127 per z
    const int r0 = slot * 16;
    if (t < 16) {
      const float4* pp = (const float4*)(partials + ((long)z * NS + r0 + t) * 32);
      float s = 0.f;
#pragma unroll
      for (int j = 0; j < 8; ++j) { float4 f = pp[j]; s += f.x + f.y + f.z + f.w; }
      sInv[t] = 1.0f / s;
    }
    __syncthreads();
    const u16* src = attnB + ((long)z * NS + r0) * NS + t * 8;
    float* dst = attnF + ((long)z * NS + r0) * NS + t * 8;
#pragma unroll
    for (int j = 0; j < 16; ++j) {
      short8 w = *(const short8*)(src + (long)j * NS);
      const float iv = sInv[j];
      float* d = dst + (long)j * NS;
      *(float4*)d = make_float4(bf2f(w[0]) * iv, bf2f(w[1]) * iv,
                                bf2f(w[2]) * iv, bf2f(w[3]) * iv);
      *(float4*)(d + 4) = make_float4(bf2f(w[4]) * iv, bf2f(w[5]) * iv,
                                      bf2f(w[6]) * iv, bf2f(w[7]) * iv);
    }
  }
}

extern "C" void kernel_launch(void* const* d_in, const int* in_sizes, int n_in,
                              void* d_out, int out_size, void* d_ws, size_t ws_size,
                              hipStream_t stream)
{
  const float* x   = (const float*)d_in[0];
  const int*   idx = (const int*)d_in[1];
  const float* Wq  = (const float*)d_in[2];
  const float* Wk  = (const float*)d_in[4];
  const float* Wv  = (const float*)d_in[6];
  const float* Wo  = (const float*)d_in[8];

  float* y     = (float*)d_out;                    // (B,S,H) fp32
  float* attnF = y + (long)NB * BS * BH;           // (B,NS,NS) fp32

  // Workspace, peak 107 MiB:
  char* ws = (char*)d_ws;
  float* partials = (float*)ws;                    // (B*NS,32) f32, 1 MiB
  u16* xs    = (u16*)(ws + (1l << 20));            // (B,NS,H)     16 MiB
  u16* qk    = (u16*)(ws + (17l << 20));           // (B,NS,2048)  32 MiB
  u16* V2T   = (u16*)(ws + (49l << 20));           // (B,H,NS)     16 MiB
  u16* attnB = (u16*)(ws + (65l << 20));           // (B,NS,NS)    32 MiB
  u16* Wqkb  = (u16*)(ws + (97l << 20));           // (2048,1024)   4 MiB
  u16* Wob   = (u16*)(ws + (101l << 20));          // (1024,1024)   2 MiB
  u16* WvT   = (u16*)(ws + (103l << 20));          // (1024,1024)   2 MiB
  u16* Wvo   = (u16*)(ws + (105l << 20));          // (1024,1024)   2 MiB

  dim3 blk(256);

  cast_gather<<<dim3(11520), blk, 0, stream>>>(Wq, Wk, Wv, Wo, x, idx,
                                               Wqkb, Wob, WvT, xs);

  qk_wvo<<<dim3(16, 17, NB), blk, 0, stream>>>(xs, Wqkb, Wob, WvT, qk, Wvo);

  scores_v2t_zero<<<dim3(16, 32, NB), blk, 0, stream>>>(qk, Wvo, xs, attnB,
                                                        V2T, partials, y);

  final_norm<<<dim3(8, 32, NB), blk, 0, stream>>>(attnB, V2T, partials,
                                                  idx, y, attnF);
}

// Round 7
// 392.474 us; speedup vs baseline: 1.0419x; 1.0079x over previous
//
#include <hip/hip_runtime.h>
#include <stdint.h>

// B=4, S=4096, H=1024, NS=2048. fp32 in/out; bf16 MFMA compute.
// Pipeline (v never materialized; attn normalized lazily from bf16 E):
//   y_sampled = softmax(q k^T/32) @ V2,  V2T = (Wo Wv) @ xs^T
//   L1: cast Wq,Wk -> Wqkb, Wo -> Wob, Wv -> WvT (transposed); gather xs.
//   L2: qk = xs @ Wqkb^T (1024 blocks) + Wvo = Wob @ WvT^T (64)
//   L3: E = exp(qk^T/32) -> attnB bf16 + row partial sums (no max subtraction:
//       scores ~ N(0,1), fp32-exact)  +  V2T = Wvo @ xs^T (512) + zero-y (512)
//   L4: y[idx rows] = (attnB @ V2T^T) * inv_rowsum (scatter, 512 blocks);
//       each block then normalizes 16 rows of attnF as a post-epilogue tail
//       (even distribution — r6's separate filler blocks drained early and
//       left half the CU slots idle for ~90us).
//
// NEW (r7): bijective XCD-aware block swizzle on all GEMM launches. Per-z
// grids are all divisible by 8, so t = (lin&7)*(nwg/8) + lin/8 is exact.
// Decode keeps consecutive same-XCD tiles on the same A-slab (512 KB -> L2)
// and makes small B operands (Wqkb 4 MiB, V2T 4 MiB/batch) XCD-L2-resident.
// r6 measured final_norm FETCH=168MB vs 48MB unique input = cross-XCD re-reads.
#define NB 4
#define BS 4096
#define BH 1024
#define NS 2048

typedef unsigned short u16;
typedef __attribute__((ext_vector_type(8))) short short8;
typedef __attribute__((ext_vector_type(4))) float float4v;

__device__ __forceinline__ void gload_lds16(const u16* g, u16* l) {
  __builtin_amdgcn_global_load_lds(
      (const __attribute__((address_space(1))) unsigned int*)g,
      (__attribute__((address_space(3))) unsigned int*)l,
      16, 0, 0);
}

__device__ __forceinline__ u16 f2bf(float f) {  // RNE float->bf16
  union { float f; unsigned u; } c; c.f = f;
  unsigned r = c.u + 0x7fff + ((c.u >> 16) & 1);
  return (u16)(r >> 16);
}

__device__ __forceinline__ float bf2f(short b) {
  union { unsigned u; float f; } c;
  c.u = ((unsigned)(unsigned short)b) << 16;
  return c.f;
}

// XCD swizzle: hardware assigns XCD = dispatch_index % 8. Map so each XCD
// gets a CONTIGUOUS chunk of logical tiles. Requires nwg % 8 == 0 (all our
// per-z grids are). Bijective by construction.
__device__ __forceinline__ int xswz(int lin, int nwg) {
  return (lin & 7) * (nwg >> 3) + (lin >> 3);
}

// L1: casts + Wv transpose + gather. Grid 11520 x 256.
__global__ __launch_bounds__(256)
void cast_gather(const float* __restrict__ Wq, const float* __restrict__ Wk,
                 const float* __restrict__ Wv, const float* __restrict__ Wo,
                 const float* __restrict__ x, const int* __restrict__ idx,
                 u16* __restrict__ Wqkb, u16* __restrict__ Wob,
                 u16* __restrict__ WvT, u16* __restrict__ xs)
{
  __shared__ __align__(16) u16 tile[64][80];
  const int t = threadIdx.x;
  const int b = blockIdx.x;
  if (b < 3072) {
    long i = ((long)(b & 1023)) * 1024 + t * 4;
    const float* src; u16* dst;
    if (b < 1024)      { src = Wq + i; dst = Wqkb + i; }
    else if (b < 2048) { src = Wk + i; dst = Wqkb + (1l << 20) + i; }
    else               { src = Wo + i; dst = Wob + i; }
    float4 f = *(const float4*)src;
    u16 o[4] = { f2bf(f.x), f2bf(f.y), f2bf(f.z), f2bf(f.w) };
    *(uint2*)dst = *(const uint2*)o;
  } else if (b < 3328) {
    const int id = b - 3072;                 // 16x16 tiles of 64x64
    const int tr = id >> 4, tc = id & 15;
    const int hl = t >> 2, c0 = (t & 3) * 16;
    const float* src = Wv + ((long)(tr * 64 + hl)) * 1024 + tc * 64 + c0;
    u16 tmp[16];
#pragma unroll
    for (int j = 0; j < 4; ++j) {
      float4 f = ((const float4*)src)[j];
      tmp[j*4+0] = f2bf(f.x); tmp[j*4+1] = f2bf(f.y);
      tmp[j*4+2] = f2bf(f.z); tmp[j*4+3] = f2bf(f.w);
    }
    *(uint4*)&tile[hl][c0]     = *(const uint4*)&tmp[0];
    *(uint4*)&tile[hl][c0 + 8] = *(const uint4*)&tmp[8];
    __syncthreads();
    const int gl = t >> 2;
    u16 o[16];
#pragma unroll
    for (int j = 0; j < 16; ++j) o[j] = tile[c0 + j][gl];
    u16* dst = WvT + ((long)(tc * 64 + gl)) * 1024 + tr * 64 + c0;
    *(uint4*)dst       = *(const uint4*)&o[0];
    *(uint4*)(dst + 8) = *(const uint4*)&o[8];
  } else {
    const int id = b - 3328;
    const int bb = id >> 11, i = id & 2047;
    const float* src = x + ((long)bb * BS + idx[i]) * BH + t * 4;
    u16* dst = xs + ((long)bb * NS + i) * BH + t * 4;
    float4 f = *(const float4*)src;
    u16 o[4] = { f2bf(f.x), f2bf(f.y), f2bf(f.z), f2bf(f.w) };
    *(uint2*)dst = *(const uint2*)o;
  }
}

// ---------------------------------------------------------------------------
// Core 128x128 tile GEMM, BK=64: C = alpha * (A-rows x B-rows^T), bf16,
// K-contig. 4 waves (2x2 of 64x64). LDS 2x16KB, octet-XOR swizzle; staging
// and fragment reads both conflict-free. C rows optionally scattered via sC.
// EPI=0: plain store.
// EPI=1: vv=exp(vv); store bf16 to C; per-row 64-col partial sums ->
//        auxP[row*32 + bx*2 + wn]  (no atomics, no zeroing).
// EPI=2: pre-loop inv[128] from auxP (shared sInv2); epilogue row-scales
//        by inv before store.
// ---------------------------------------------------------------------------
template <typename OutT, int EPI>
__device__ __forceinline__ void gemm_core(
    u16* __restrict__ ldsA, u16* __restrict__ ldsB,
    const u16* __restrict__ Az, int lda,
    const u16* __restrict__ Bz, int ldb,
    OutT* __restrict__ Cz, const int* __restrict__ sC, int ldc,
    int K, float alpha, int bx, int by,
    float* __restrict__ auxP)
{
  __shared__ float sInv2[128];             // used only by EPI=2 (512 B)
  const int t = threadIdx.x;
  const int l = t & 63;
  const int wm = t >> 7, wn = (t >> 6) & 1;

  const int sr = t >> 3;                   // staging row 0..31
  const int scol = (t & 7) ^ (sr & 7);     // logical k-chunk to fetch
  const u16* aS = Az + (long)(by * 128 + sr) * lda + scol * 8;
  const u16* bS = Bz + (long)(bx * 128 + sr) * ldb + scol * 8;
  const long aStep = 32l * lda, bStep = 32l * ldb;

  int aOff[4][2], bOff[4][2];
#pragma unroll
  for (int i = 0; i < 4; ++i) {
#pragma unroll
    for (int h = 0; h < 2; ++h) {
      int rA = wm * 64 + i * 16 + (l & 15);
      aOff[i][h] = rA * 128 + (((h * 4 + (l >> 4)) ^ (rA & 7)) * 16);
      int rB = wn * 64 + i * 16 + (l & 15);
      bOff[i][h] = rB * 128 + (((h * 4 + (l >> 4)) ^ (rB & 7)) * 16);
    }
  }

  if constexpr (EPI == 2) {
    if (t < 128) {
      const float4* pp = (const float4*)(auxP + (long)(by * 128 + t) * 32);
      float s = 0.f;
#pragma unroll
      for (int j = 0; j < 8; ++j) { float4 f = pp[j]; s += f.x + f.y + f.z + f.w; }
      sInv2[t] = 1.0f / s;
    }
    __syncthreads();
  }

  float4v acc[4][4] = {};

  for (int k0 = 0; k0 < K; k0 += 64) {
    __syncthreads();
    gload_lds16(aS + k0,             ldsA + t * 8);
    gload_lds16(aS + aStep + k0,     ldsA + 2048 + t * 8);
    gload_lds16(aS + 2 * aStep + k0, ldsA + 4096 + t * 8);
    gload_lds16(aS + 3 * aStep + k0, ldsA + 6144 + t * 8);
    gload_lds16(bS + k0,             ldsB + t * 8);
    gload_lds16(bS + bStep + k0,     ldsB + 2048 + t * 8);
    gload_lds16(bS + 2 * bStep + k0, ldsB + 4096 + t * 8);
    gload_lds16(bS + 3 * bStep + k0, ldsB + 6144 + t * 8);
    __syncthreads();

#pragma unroll
    for (int h = 0; h < 2; ++h) {
      short8 af[4], bfr[4];
#pragma unroll
      for (int i = 0; i < 4; ++i) af[i]  = *(const short8*)((const char*)ldsA + aOff[i][h]);
#pragma unroll
      for (int i = 0; i < 4; ++i) bfr[i] = *(const short8*)((const char*)ldsB + bOff[i][h]);
#pragma unroll
      for (int mi = 0; mi < 4; ++mi)
#pragma unroll
        for (int ni = 0; ni < 4; ++ni)
          acc[mi][ni] = __builtin_amdgcn_mfma_f32_16x16x32_bf16(af[mi], bfr[ni], acc[mi][ni], 0, 0, 0);
    }
  }

  // Epilogue. C/D layout: col = l&15, row = (l>>4)*4 + reg.
#pragma unroll
  for (int mi = 0; mi < 4; ++mi) {
#pragma unroll
    for (int i = 0; i < 4; ++i) {
      const int rloc = wm * 64 + mi * 16 + ((l >> 4) * 4) + i;
      const int r = by * 128 + rloc;
      const long rowOff = (long)(sC ? sC[r] : r) * ldc;
      float rs = 1.0f;
      if constexpr (EPI == 2) rs = sInv2[rloc];
      float psum = 0.f;
#pragma unroll
      for (int ni = 0; ni < 4; ++ni) {
        const int c = bx * 128 + wn * 64 + ni * 16 + (l & 15);
        float vv = acc[mi][ni][i] * alpha;
        if constexpr (EPI == 1) {
          vv = __expf(vv);
          psum += vv;
          Cz[rowOff + c] = (OutT)f2bf(vv);
        } else if constexpr (EPI == 2) {
          Cz[rowOff + c] = (OutT)(vv * rs);
        } else {
          if constexpr (sizeof(OutT) == 2) Cz[rowOff + c] = (OutT)f2bf(vv);
          else                             Cz[rowOff + c] = (OutT)vv;
        }
      }
      if constexpr (EPI == 1) {
        psum += __shfl_xor(psum, 1);
        psum += __shfl_xor(psum, 2);
        psum += __shfl_xor(psum, 4);
        psum += __shfl_xor(psum, 8);
        if ((l & 15) == 0) auxP[(long)r * 32 + bx * 2 + wn] = psum;
      }
    }
  }
}

// L2: qk (t<256) + Wvo (t in [256,272)). Grid (16,17,NB) = 1088; per-z 272.
__global__ __launch_bounds__(256, 4)
void qk_wvo(const u16* __restrict__ xs, const u16* __restrict__ Wqkb,
            const u16* __restrict__ Wob, const u16* __restrict__ WvT,
            u16* __restrict__ qk, u16* __restrict__ Wvo)
{
  __shared__ __align__(16) u16 ldsA[128 * 64];
  __shared__ __align__(16) u16 ldsB[128 * 64];
  const long z = blockIdx.z;
  const int tt = xswz(blockIdx.y * 16 + blockIdx.x, 272);
  if (tt < 256) {
    gemm_core<u16, 0>(ldsA, ldsB, xs + z * ((long)NS * BH), BH, Wqkb, BH,
                      qk + z * ((long)NS * 2048), nullptr, 2048, BH, 1.0f,
                      tt & 15, tt >> 4, nullptr);
  } else {
    const int id = (int)z * 16 + (tt - 256);   // 0..63 -> 8x8 tiles
    gemm_core<u16, 0>(ldsA, ldsB, Wob, BH, WvT, BH,
                      Wvo, nullptr, BH, BH, 1.0f,
                      id & 7, id >> 3, nullptr);
  }
}

// L3: scores E=exp (t<256) + V2T (t in [256,384)) + zero-y (t in [384,512)).
// Grid (16,32,NB) = 2048; per-z 512.
__global__ __launch_bounds__(256, 4)
void scores_v2t_zero(const u16* __restrict__ qk, const u16* __restrict__ Wvo,
                     const u16* __restrict__ xs,
                     u16* __restrict__ attnB, u16* __restrict__ V2T,
                     float* __restrict__ partials, float* __restrict__ y)
{
  __shared__ __align__(16) u16 ldsA[128 * 64];
  __shared__ __align__(16) u16 ldsB[128 * 64];
  const long z = blockIdx.z;
  const int tt = xswz(blockIdx.y * 16 + blockIdx.x, 512);
  if (tt < 256) {
    const u16* A = qk + z * ((long)NS * 2048);
    gemm_core<u16, 1>(ldsA, ldsB, A, 2048, A + 1024, 2048,
                      attnB + z * ((long)NS * NS), nullptr, NS, BH, 0.03125f,
                      tt & 15, tt >> 4,
                      partials + z * ((long)NS * 32));
  } else if (tt < 384) {
    const int u = tt - 256;
    gemm_core<u16, 0>(ldsA, ldsB, Wvo, BH, xs + z * ((long)NS * BH), BH,
                      V2T + z * ((long)BH * NS), nullptr, NS, BH, 1.0f,
                      u & 15, u >> 4, nullptr);
  } else {
    long id = (long)(tt - 384) + z * 128;      // 0..511, 128 KiB each
    float4* p = (float4*)y + id * 8192 + threadIdx.x;
#pragma unroll
    for (int j = 0; j < 32; ++j) p[j * 256] = make_float4(0.f, 0.f, 0.f, 0.f);
  }
}

// L4: y[idx rows] = (attnB @ V2T^T) * inv (scatter). Grid (8,16,NB) = 512,
// per-z 128, all GEMM. Post-epilogue tail: each block normalizes 16 rows of
// attnF = bf2f(attnB) * inv (evenly distributed -> no straggler blocks).
__global__ __launch_bounds__(256, 4)
void final_norm(const u16* __restrict__ attnB, const u16* __restrict__ V2T,
                const float* __restrict__ partials, const int* __restrict__ idx,
                float* __restrict__ y, float* __restrict__ attnF)
{
  __shared__ __align__(16) u16 ldsA[128 * 64];
  __shared__ __align__(16) u16 ldsB[128 * 64];
  __shared__ float sInvT[16];
  const long z = blockIdx.z;
  const int tt = xswz(blockIdx.y * 8 + blockIdx.x, 128);
  gemm_core<float, 2>(ldsA, ldsB, attnB + z * ((long)NS * NS), NS,
                      V2T + z * ((long)BH * NS), NS,
                      y + z * ((long)BS * BH), idx, BH, NS, 1.0f,
                      tt & 7, tt >> 3,
                      (float*)(partials + z * ((long)NS * 32)));

  // Tail: normalize rows [tt*16, tt*16+16) of this batch's attnF.
  const int th = threadIdx.x;
  const int r0 = tt * 16;
  if (th < 16) {
    const float4* pp = (const float4*)(partials + ((long)z * NS + r0 + th) * 32);
    float s = 0.f;
#pragma unroll
    for (int j = 0; j < 8; ++j) { float4 f = pp[j]; s += f.x + f.y + f.z + f.w; }
    sInvT[th] = 1.0f / s;
  }
  __syncthreads();
  const u16* src = attnB + ((long)z * NS + r0) * NS + th * 8;
  float* dst = attnF + ((long)z * NS + r0) * NS + th * 8;
#pragma unroll
  for (int j = 0; j < 16; ++j) {
    short8 w = *(const short8*)(src + (long)j * NS);
    const float iv = sInvT[j];
    float* d = dst + (long)j * NS;
    *(float4*)d = make_float4(bf2f(w[0]) * iv, bf2f(w[1]) * iv,
                              bf2f(w[2]) * iv, bf2f(w[3]) * iv);
    *(float4*)(d + 4) = make_float4(bf2f(w[4]) * iv, bf2f(w[5]) * iv,
                                    bf2f(w[6]) * iv, bf2f(w[7]) * iv);
  }
}

extern "C" void kernel_launch(void* const* d_in, const int* in_sizes, int n_in,
                              void* d_out, int out_size, void* d_ws, size_t ws_size,
                              hipStream_t stream)
{
  const float* x   = (const float*)d_in[0];
  const int*   idx = (const int*)d_in[1];
  const float* Wq  = (const float*)d_in[2];
  const float* Wk  = (const float*)d_in[4];
  const float* Wv  = (const float*)d_in[6];
  const float* Wo  = (const float*)d_in[8];

  float* y     = (float*)d_out;                    // (B,S,H) fp32
  float* attnF = y + (long)NB * BS * BH;           // (B,NS,NS) fp32

  // Workspace, peak 107 MiB:
  char* ws = (char*)d_ws;
  float* partials = (float*)ws;                    // (B*NS,32) f32, 1 MiB
  u16* xs    = (u16*)(ws + (1l << 20));            // (B,NS,H)     16 MiB
  u16* qk    = (u16*)(ws + (17l << 20));           // (B,NS,2048)  32 MiB
  u16* V2T   = (u16*)(ws + (49l << 20));           // (B,H,NS)     16 MiB
  u16* attnB = (u16*)(ws + (65l << 20));           // (B,NS,NS)    32 MiB
  u16* Wqkb  = (u16*)(ws + (97l << 20));           // (2048,1024)   4 MiB
  u16* Wob   = (u16*)(ws + (101l << 20));          // (1024,1024)   2 MiB
  u16* WvT   = (u16*)(ws + (103l << 20));          // (1024,1024)   2 MiB
  u16* Wvo   = (u16*)(ws + (105l << 20));          // (1024,1024)   2 MiB

  dim3 blk(256);

  cast_gather<<<dim3(11520), blk, 0, stream>>>(Wq, Wk, Wv, Wo, x, idx,
                                               Wqkb, Wob, WvT, xs);

  qk_wvo<<<dim3(16, 17, NB), blk, 0, stream>>>(xs, Wqkb, Wob, WvT, qk, Wvo);

  scores_v2t_zero<<<dim3(16, 32, NB), blk, 0, stream>>>(qk, Wvo, xs, attnB,
                                                        V2T, partials, y);

  final_norm<<<dim3(8, 16, NB), blk, 0, stream>>>(attnB, V2T, partials,
                                                  idx, y, attnF);
}